// Round 7
// baseline (1509.098 us; speedup 1.0000x reference)
//
#include <hip/hip_runtime.h>
#include <math.h>

// out = softmax(s @ X[:-1]^T) @ X[1:]
//   X: (8192,1024) fp32, s: (8191,1024) fp32, out: (8191,1024) fp32
// R9 = R5 structure at NW=16 (1024-thread blocks) + register ping-pong
// prefetch (retry of R6's mechanism with real VGPR headroom: 64 AGPR acc).
//   wave w: QK keys [16w,16w+16), PV d-chunk [64w,64w+64).
//   Per-CU streaming rate 26.4->31.5 GB/s expected from 8->16 waves (R2 ref).

#define NQ 8191
#define NK 8191
#define DD 1024
#define BQ 64
#define BK 256
#define KSPLIT 2
#define KHALF 4096
#define ITERS 16
#define NW 16
#define NT 1024
#define QKK 30         // Q k-groups in LDS; groups 30,31 live in registers

typedef _Float16 half8 __attribute__((ext_vector_type(8)));
typedef float float4v __attribute__((ext_vector_type(4)));

// Kf[g=key/16][kk=d/32][lane][8]: lane l holds K[g*16+(l&15)][kk*32+(l>>4)*8+e]
__global__ void prep_kf(const float* __restrict__ X, _Float16* __restrict__ Kf) {
    int b = blockIdx.x * 256 + threadIdx.x;
    int l  = b & 63;
    int kk = (b >> 6) & 31;
    int g  = b >> 11;
    int row = g * 16 + (l & 15);
    int col = kk * 32 + ((l >> 4) << 3);
    const float4v* src = (const float4v*)&X[(size_t)row * DD + col];
    float4v v0 = src[0], v1 = src[1];
    half8 h;
    h[0]=(_Float16)v0[0]; h[1]=(_Float16)v0[1]; h[2]=(_Float16)v0[2]; h[3]=(_Float16)v0[3];
    h[4]=(_Float16)v1[0]; h[5]=(_Float16)v1[1]; h[6]=(_Float16)v1[2]; h[7]=(_Float16)v1[3];
    *(half8*)&Kf[(size_t)b * 8] = h;
}

// Vf[h=d/16][kkg=key/32][lane][8]: lane l holds V^T[h*16+(l&15)][kkg*32+(l>>4)*8+e]
__global__ void prep_vf(const float* __restrict__ X, _Float16* __restrict__ Vf) {
    int b = blockIdx.x * 256 + threadIdx.x;
    int l   = b & 63;
    int kkg = (b >> 6) & 255;
    int h   = b >> 14;
    int d    = h * 16 + (l & 15);
    int key0 = kkg * 32 + ((l >> 4) << 3);
    half8 hv;
    #pragma unroll
    for (int e = 0; e < 8; ++e) {
        int row = key0 + e + 1;
        float v = (row < 8192) ? X[(size_t)row * DD + d] : 0.f;
        hv[e] = (_Float16)v;
    }
    *(half8*)&Vf[(size_t)b * 8] = hv;
}

#define LOADV(BUF, KK2)                                                       \
    _Pragma("unroll")                                                         \
    for (int dt = 0; dt < 4; ++dt)                                            \
        BUF[dt] = *(const half8*)(vp + (size_t)dt * 131072 + (KK2) * 512);

#define MFMAV(BUF, KK2)                                                       \
    {                                                                         \
        half8 pa[4];                                                          \
        _Pragma("unroll")                                                     \
        for (int qf = 0; qf < 4; ++qf)                                        \
            pa[qf] = *(const half8*)&Pf[((qf * 8 + (KK2)) * 64 + l) * 8];     \
        _Pragma("unroll")                                                     \
        for (int dt = 0; dt < 4; ++dt)                                        \
            _Pragma("unroll")                                                 \
            for (int qf = 0; qf < 4; ++qf)                                    \
                o[qf][dt] = __builtin_amdgcn_mfma_f32_16x16x32_f16(pa[qf], BUF[dt], o[qf][dt], 0, 0, 0); \
    }

__launch_bounds__(NT, 1)
__global__ void flash(const float* __restrict__ s,
                      const _Float16* __restrict__ Kf,
                      const _Float16* __restrict__ Vf,
                      _Float16* __restrict__ Op,
                      float2* __restrict__ ml) {
    __shared__ _Float16 Qf[4 * QKK * 64 * 8];   // 122,880 B fragment-linear
    __shared__ _Float16 Pf[4 * 8 * 64 * 8];     // 32,768 B fragment-linear
    __shared__ float    Rm[BQ * NW];            // [row][wave] 4,096 B

    const int t  = threadIdx.x;
    const int w  = t >> 6;       // wave 0..15
    const int l  = t & 63;
    const int ln = l & 15;
    const int q4 = l >> 4;

    const int bid = blockIdx.x;
    const int qt  = bid >> 1;
    const int ks  = bid & 1;
    const int q0  = qt * BQ;

    // ---- stage Q: fragment-linear LDS (groups 0..29), groups 30,31 in regs ----
    for (int e = t; e < 4 * QKK * 64; e += NT) {
        int ll  = e & 63;
        int rem = e >> 6;
        int kk  = rem % QKK;
        int qf  = rem / QKK;
        int row = qf * 16 + (ll & 15);
        int col = kk * 32 + ((ll >> 4) << 3);
        half8 hv;
        if (q0 + row < NQ) {
            const float4v* src = (const float4v*)&s[(size_t)(q0 + row) * DD + col];
            float4v v0 = src[0], v1 = src[1];
            hv[0]=(_Float16)v0[0]; hv[1]=(_Float16)v0[1]; hv[2]=(_Float16)v0[2]; hv[3]=(_Float16)v0[3];
            hv[4]=(_Float16)v1[0]; hv[5]=(_Float16)v1[1]; hv[6]=(_Float16)v1[2]; hv[7]=(_Float16)v1[3];
        } else {
            #pragma unroll
            for (int j = 0; j < 8; ++j) hv[j] = (_Float16)0.f;
        }
        *(half8*)&Qf[(size_t)e * 8] = hv;
    }
    half8 qreg[4][2];
    #pragma unroll
    for (int qf = 0; qf < 4; ++qf)
        #pragma unroll
        for (int kr = 0; kr < 2; ++kr) {
            int row = qf * 16 + ln;
            int col = (QKK + kr) * 32 + (q4 << 3);
            half8 hv;
            if (q0 + row < NQ) {
                const float4v* src = (const float4v*)&s[(size_t)(q0 + row) * DD + col];
                float4v v0 = src[0], v1 = src[1];
                hv[0]=(_Float16)v0[0]; hv[1]=(_Float16)v0[1]; hv[2]=(_Float16)v0[2]; hv[3]=(_Float16)v0[3];
                hv[4]=(_Float16)v1[0]; hv[5]=(_Float16)v1[1]; hv[6]=(_Float16)v1[2]; hv[7]=(_Float16)v1[3];
            } else {
                #pragma unroll
                for (int j = 0; j < 8; ++j) hv[j] = (_Float16)0.f;
            }
            qreg[qf][kr] = hv;
        }
    __syncthreads();

    // O accumulator: wave w owns D chunk [w*64, w*64+64): 4 qf x 4 dt
    float4v o[4][4];
    #pragma unroll
    for (int qf = 0; qf < 4; ++qf)
        #pragma unroll
        for (int dt = 0; dt < 4; ++dt)
            o[qf][dt] = (float4v){0.f, 0.f, 0.f, 0.f};

    float m_run[16], l_run[16];
    #pragma unroll
    for (int i = 0; i < 16; ++i) { m_run[i] = -INFINITY; l_run[i] = 0.f; }

    // Pf write base (halfs): element (row=qf*16+q4*4+r, key=w*16+ln)
    const int pbase = (w >> 1) * 512 + ((w & 1) * 2 + (ln >> 3)) * 128
                      + q4 * 32 + (ln & 7);

    half8 va[4], vb[4];

    for (int it = 0; it < ITERS; ++it) {
        // ---- phase 1: S[64 q][wave's 16 keys], full-D, 4-deep K prefetch ----
        const _Float16* kp0 = Kf + (size_t)(ks * 256 + it * 16 + w) * 16384
                              + (size_t)l * 8;
        float4v sa[4];
        #pragma unroll
        for (int qf = 0; qf < 4; ++qf)
            sa[qf] = (float4v){0.f, 0.f, 0.f, 0.f};

        half8 kbuf[4];
        #pragma unroll
        for (int j = 0; j < 4; ++j)
            kbuf[j] = *(const half8*)(kp0 + j * 512);

        #pragma unroll
        for (int kk = 0; kk < 32; ++kk) {
            half8 kf8 = kbuf[kk & 3];
            if (kk + 4 < 32)
                kbuf[kk & 3] = *(const half8*)(kp0 + (kk + 4) * 512);
            #pragma unroll
            for (int qf = 0; qf < 4; ++qf) {
                half8 qa = (kk < QKK)
                    ? *(const half8*)&Qf[((qf * QKK + kk) * 64 + l) * 8]
                    : qreg[qf][kk - QKK];
                sa[qf] = __builtin_amdgcn_mfma_f32_16x16x32_f16(qa, kf8, sa[qf], 0, 0, 0);
            }
        }

        const int kbase = ks * KHALF + it * BK + w * 16;
        const bool bad0 = (kbase + ln) >= NK;   // only key 8191 ever bad

        // ---- wave-local row max over this wave's 16 keys ----
        float pm[16];
        #pragma unroll
        for (int qf = 0; qf < 4; ++qf)
            #pragma unroll
            for (int r = 0; r < 4; ++r)
                pm[qf * 4 + r] = bad0 ? -INFINITY : sa[qf][r];
        #pragma unroll
        for (int i = 0; i < 16; ++i) {
            float v = pm[i];
            v = fmaxf(v, __shfl_xor(v, 1, 64));
            v = fmaxf(v, __shfl_xor(v, 2, 64));
            v = fmaxf(v, __shfl_xor(v, 4, 64));
            v = fmaxf(v, __shfl_xor(v, 8, 64));
            pm[i] = v;
        }
        if (ln == 0) {
            #pragma unroll
            for (int qf = 0; qf < 4; ++qf)
                #pragma unroll
                for (int r = 0; r < 4; ++r)
                    Rm[(qf * 16 + q4 * 4 + r) * NW + w] = pm[qf * 4 + r];
        }
        __syncthreads();   // B: Rm visible

        // ---- global row max, alpha, P, l ----
        const _Float16* vp = Vf + (size_t)(w * 4) * 131072
                             + (size_t)(ks * 128 + it * 8) * 512 + (size_t)l * 8;
        float al[16];
        #pragma unroll
        for (int qf = 0; qf < 4; ++qf)
            #pragma unroll
            for (int r = 0; r < 4; ++r) {
                int row = qf * 16 + q4 * 4 + r;
                int i = qf * 4 + r;
                float4v ra = *(const float4v*)&Rm[row * NW];
                float4v rb = *(const float4v*)&Rm[row * NW + 4];
                float4v rc = *(const float4v*)&Rm[row * NW + 8];
                float4v rd = *(const float4v*)&Rm[row * NW + 12];
                float v = fmaxf(fmaxf(fmaxf(ra[0], ra[1]), fmaxf(ra[2], ra[3])),
                                fmaxf(fmaxf(rb[0], rb[1]), fmaxf(rb[2], rb[3])));
                v = fmaxf(v, fmaxf(fmaxf(fmaxf(rc[0], rc[1]), fmaxf(rc[2], rc[3])),
                                   fmaxf(fmaxf(rd[0], rd[1]), fmaxf(rd[2], rd[3]))));
                v = fmaxf(v, m_run[i]);
                al[i] = __expf(m_run[i] - v);
                m_run[i] = v;
            }
        #pragma unroll
        for (int i = 0; i < 16; ++i) l_run[i] *= al[i];
        #pragma unroll
        for (int qf = 0; qf < 4; ++qf)
            #pragma unroll
            for (int r = 0; r < 4; ++r) {
                int i = qf * 4 + r;
                float p0 = bad0 ? 0.f : __expf(sa[qf][r] - m_run[i]);
                l_run[i] += p0;
                Pf[pbase + qf * 4096 + r * 8] = (_Float16)p0;
            }
        // rescale O
        #pragma unroll
        for (int qf = 0; qf < 4; ++qf)
            #pragma unroll
            for (int dt = 0; dt < 4; ++dt)
                #pragma unroll
                for (int r = 0; r < 4; ++r)
                    o[qf][dt][r] *= al[qf * 4 + r];
        __syncthreads();   // D: Pf ready

        // ---- phase 3: O += P . V over 256 keys, wave's 64-wide D chunk ----
        LOADV(va, 0);
        LOADV(vb, 1);  MFMAV(va, 0);
        LOADV(va, 2);  MFMAV(vb, 1);
        LOADV(vb, 3);  MFMAV(va, 2);
        LOADV(va, 4);  MFMAV(vb, 3);
        LOADV(vb, 5);  MFMAV(va, 4);
        LOADV(va, 6);  MFMAV(vb, 5);
        LOADV(vb, 7);  MFMAV(va, 6);
        MFMAV(vb, 7);
        __syncthreads();   // A: Pf/Rm free for next iter
    }

    // ---- epilogue: reduce l across lanes and waves, store partials ----
    float lt[16];
    #pragma unroll
    for (int i = 0; i < 16; ++i) {
        float v = l_run[i];
        v += __shfl_xor(v, 1, 64);
        v += __shfl_xor(v, 2, 64);
        v += __shfl_xor(v, 4, 64);
        v += __shfl_xor(v, 8, 64);
        lt[i] = v;
    }
    if (ln == 0) {
        #pragma unroll
        for (int qf = 0; qf < 4; ++qf)
            #pragma unroll
            for (int r = 0; r < 4; ++r)
                Rm[(qf * 16 + q4 * 4 + r) * NW + w] = lt[qf * 4 + r];
    }
    __syncthreads();

    float lsum[16], inv[16];
    #pragma unroll
    for (int qf = 0; qf < 4; ++qf)
        #pragma unroll
        for (int r = 0; r < 4; ++r) {
            int row = qf * 16 + q4 * 4 + r;
            float sum = 0.f;
            #pragma unroll
            for (int wv = 0; wv < NW; ++wv) sum += Rm[row * NW + wv];
            lsum[qf * 4 + r] = sum;
            inv[qf * 4 + r] = 1.f / sum;
        }

    if (w == 0 && ln == 0) {
        #pragma unroll
        for (int qf = 0; qf < 4; ++qf)
            #pragma unroll
            for (int r = 0; r < 4; ++r) {
                int row = q0 + qf * 16 + q4 * 4 + r;
                int i = qf * 4 + r;
                if (row < NQ)
                    ml[ks * 8192 + row] = make_float2(m_run[i], lsum[i]);
            }
    }

    #pragma unroll
    for (int qf = 0; qf < 4; ++qf)
        #pragma unroll
        for (int dt = 0; dt < 4; ++dt)
            #pragma unroll
            for (int r = 0; r < 4; ++r) {
                int row = q0 + qf * 16 + q4 * 4 + r;
                int col = w * 64 + dt * 16 + ln;
                if (row < NQ)
                    Op[((size_t)ks * NQ + row) * DD + col] =
                        (_Float16)(o[qf][dt][r] * inv[qf * 4 + r]);
            }
}

// out = w0 * Op[0] + w1 * Op[1], weights from (m,l) pairs
__global__ void combine(const _Float16* __restrict__ Op,
                        const float2* __restrict__ ml,
                        float* __restrict__ out) {
    size_t idx = ((size_t)blockIdx.x * 256 + threadIdx.x) * 8;
    if (idx >= (size_t)NQ * DD) return;
    int row = (int)(idx >> 10);
    float2 a = ml[row];
    float2 b = ml[8192 + row];
    float m  = fmaxf(a.x, b.x);
    float w0 = a.y * __expf(a.x - m);
    float w1 = b.y * __expf(b.x - m);
    float inv = 1.f / (w0 + w1);
    w0 *= inv; w1 *= inv;
    half8 h0 = *(const half8*)&Op[idx];
    half8 h1 = *(const half8*)&Op[(size_t)NQ * DD + idx];
    float4v o0, o1;
    #pragma unroll
    for (int e = 0; e < 4; ++e) o0[e] = w0 * (float)h0[e] + w1 * (float)h1[e];
    #pragma unroll
    for (int e = 0; e < 4; ++e) o1[e] = w0 * (float)h0[e + 4] + w1 * (float)h1[e + 4];
    *(float4v*)&out[idx]     = o0;
    *(float4v*)&out[idx + 4] = o1;
}

extern "C" void kernel_launch(void* const* d_in, const int* in_sizes, int n_in,
                              void* d_out, int out_size, void* d_ws, size_t ws_size,
                              hipStream_t stream) {
    const float* X = (const float*)d_in[0];
    const float* s = (const float*)d_in[1];
    float* out = (float*)d_out;

    _Float16* Kf = (_Float16*)d_ws;                  // 16 MiB
    _Float16* Vf = Kf + (size_t)8192 * 1024;         // 16 MiB
    _Float16* Op = Vf + (size_t)8192 * 1024;         // 32 MiB
    float2*   ml = (float2*)(Op + (size_t)2 * NQ * DD);  // 128 KiB

    prep_kf<<<4096, 256, 0, stream>>>(X, Kf);
    prep_vf<<<4096, 256, 0, stream>>>(X, Vf);
    flash<<<KSPLIT * ((NQ + BQ - 1) / BQ), NT, 0, stream>>>(s, Kf, Vf, Op, ml);
    combine<<<4096, 256, 0, stream>>>(Op, ml, out);
}

// Round 8
// 744.213 us; speedup vs baseline: 2.0278x; 2.0278x over previous
//
#include <hip/hip_runtime.h>
#include <math.h>

// out = softmax(s @ X[:-1]^T) @ X[1:]
//   X: (8192,1024) fp32, s: (8191,1024) fp32, out: (8191,1024) fp32
// R10 = R5 + V-phase streamed via global_load_lds into wave-private 3-slot
// LDS rings (static vmcnt counts; phase 3 has no other VMEM so counts are
// exact). Qf shrunk to 19 k-groups; Q k-groups 19..31 read per-iter from
// fragment-ordered Qg (compiler-managed, phase 1 only).
// Register discipline: per-wave ~230 <= 256 (2 waves/SIMD class).

#define NQ 8191
#define NK 8191
#define DD 1024
#define BQ 64
#define BK 256
#define KSPLIT 2
#define KHALF 4096
#define ITERS 16
#define NW 8
#define NT 512
#define QKK 19         // Q k-groups in LDS; groups 19..31 from Qg per iter

typedef _Float16 half8 __attribute__((ext_vector_type(8)));
typedef float float4v __attribute__((ext_vector_type(4)));

// Kf[g=key/16][kk=d/32][lane][8]
__global__ void prep_kf(const float* __restrict__ X, _Float16* __restrict__ Kf) {
    int b = blockIdx.x * 256 + threadIdx.x;
    int l  = b & 63;
    int kk = (b >> 6) & 31;
    int g  = b >> 11;
    int row = g * 16 + (l & 15);
    int col = kk * 32 + ((l >> 4) << 3);
    const float4v* src = (const float4v*)&X[(size_t)row * DD + col];
    float4v v0 = src[0], v1 = src[1];
    half8 h;
    h[0]=(_Float16)v0[0]; h[1]=(_Float16)v0[1]; h[2]=(_Float16)v0[2]; h[3]=(_Float16)v0[3];
    h[4]=(_Float16)v1[0]; h[5]=(_Float16)v1[1]; h[6]=(_Float16)v1[2]; h[7]=(_Float16)v1[3];
    *(half8*)&Kf[(size_t)b * 8] = h;
}

// Vf[h=d/16][kkg=key/32][lane][8], V[key][d] = X[key+1][d]
__global__ void prep_vf(const float* __restrict__ X, _Float16* __restrict__ Vf) {
    int b = blockIdx.x * 256 + threadIdx.x;
    int l   = b & 63;
    int kkg = (b >> 6) & 255;
    int h   = b >> 14;
    int d    = h * 16 + (l & 15);
    int key0 = kkg * 32 + ((l >> 4) << 3);
    half8 hv;
    #pragma unroll
    for (int e = 0; e < 8; ++e) {
        int row = key0 + e + 1;
        float v = (row < 8192) ? X[(size_t)row * DD + d] : 0.f;
        hv[e] = (_Float16)v;
    }
    *(half8*)&Vf[(size_t)b * 8] = hv;
}

// Qg[qt][qf][kk][lane][8]: lane l holds s[qt*64+qf*16+(l&15)][kk*32+(l>>4)*8+e]
__global__ void prep_qf(const float* __restrict__ s, _Float16* __restrict__ Qg) {
    int b = blockIdx.x * 256 + threadIdx.x;
    int l  = b & 63;
    int kk = (b >> 6) & 31;
    int qf = (b >> 11) & 3;
    int qt = b >> 13;
    int row = qt * 64 + qf * 16 + (l & 15);
    int col = kk * 32 + ((l >> 4) << 3);
    half8 hv;
    if (row < NQ) {
        const float4v* src = (const float4v*)&s[(size_t)row * DD + col];
        float4v v0 = src[0], v1 = src[1];
        hv[0]=(_Float16)v0[0]; hv[1]=(_Float16)v0[1]; hv[2]=(_Float16)v0[2]; hv[3]=(_Float16)v0[3];
        hv[4]=(_Float16)v1[0]; hv[5]=(_Float16)v1[1]; hv[6]=(_Float16)v1[2]; hv[7]=(_Float16)v1[3];
    } else {
        #pragma unroll
        for (int j = 0; j < 8; ++j) hv[j] = (_Float16)0.f;
    }
    *(half8*)&Qg[(size_t)b * 8] = hv;
}

__device__ __forceinline__ void gld16(const _Float16* g, _Float16* lp) {
    __builtin_amdgcn_global_load_lds(
        (const __attribute__((address_space(1))) unsigned int*)g,
        (__attribute__((address_space(3))) unsigned int*)lp, 16, 0, 0);
}

#define W4 do { asm volatile("s_waitcnt vmcnt(4)" ::: "memory"); \
                __builtin_amdgcn_sched_barrier(0); } while (0)
#define W2 do { asm volatile("s_waitcnt vmcnt(2)" ::: "memory"); \
                __builtin_amdgcn_sched_barrier(0); } while (0)
#define W0 do { asm volatile("s_waitcnt vmcnt(0)" ::: "memory"); \
                __builtin_amdgcn_sched_barrier(0); } while (0)
#define NOWAIT ((void)0)
#define NOFILL ((void)0)

// fill ring slot with V frags (DT0, DT0+1) at key-slice KK2N
#define IVF(ARR, DT0, KK2N) do { \
    gld16(vbase + (((size_t)(w * 8 + (DT0)    ) * 256 + (KK2N)) << 9), &ARR[w][0][0]); \
    gld16(vbase + (((size_t)(w * 8 + (DT0) + 1) * 256 + (KK2N)) << 9), &ARR[w][1][0]); \
} while (0)

// consume ring slot: sub-step S (kk2=S>>2, dt0=(S&3)*2), 8 MFMAs
#define PV3(S, ARR, WAITM, FILLC) do { \
    WAITM; \
    if (((S) & 3) == 0) { \
        _Pragma("unroll") \
        for (int qf_ = 0; qf_ < 4; ++qf_) \
            pa[qf_] = *(const half8*)&Pf[((qf_ * 8 + ((S) >> 2)) * 64 + l) * 8]; \
    } \
    { \
        half8 v0_ = *(const half8*)&ARR[w][0][l * 8]; \
        half8 v1_ = *(const half8*)&ARR[w][1][l * 8]; \
        _Pragma("unroll") \
        for (int qf_ = 0; qf_ < 4; ++qf_) { \
            o[qf_][((S) & 3) * 2]     = __builtin_amdgcn_mfma_f32_16x16x32_f16(pa[qf_], v0_, o[qf_][((S) & 3) * 2], 0, 0, 0); \
            o[qf_][((S) & 3) * 2 + 1] = __builtin_amdgcn_mfma_f32_16x16x32_f16(pa[qf_], v1_, o[qf_][((S) & 3) * 2 + 1], 0, 0, 0); \
        } \
    } \
    FILLC; \
} while (0)

__launch_bounds__(NT, 2)
__global__ void flash(const float* __restrict__ s,
                      const _Float16* __restrict__ Qg,
                      const _Float16* __restrict__ Kf,
                      const _Float16* __restrict__ Vf,
                      _Float16* __restrict__ Op,
                      float2* __restrict__ ml) {
    __shared__ _Float16 Qf[4 * QKK * 64 * 8];   // 77,824 B fragment-linear
    __shared__ _Float16 Pf[4 * 8 * 64 * 8];     // 32,768 B fragment-linear
    __shared__ float    Rm[NW * BQ];            // 2,048 B
    __shared__ _Float16 VSA[NW][2][512];        // 16 KB per ring slot set
    __shared__ _Float16 VSB[NW][2][512];
    __shared__ _Float16 VSC[NW][2][512];

    const int t  = threadIdx.x;
    const int w  = t >> 6;
    const int l  = t & 63;
    const int ln = l & 15;
    const int q4 = l >> 4;

    const int bid = blockIdx.x;
    const int qt  = bid >> 1;
    const int ks  = bid & 1;
    const int q0  = qt * BQ;

    // ---- stage Q k-groups 0..18 into fragment-linear LDS ----
    for (int e = t; e < 4 * QKK * 64; e += NT) {
        int ll  = e & 63;
        int rem = e >> 6;
        int kk  = rem % QKK;
        int qf  = rem / QKK;
        int row = qf * 16 + (ll & 15);
        int col = kk * 32 + ((ll >> 4) << 3);
        half8 hv;
        if (q0 + row < NQ) {
            const float4v* src = (const float4v*)&s[(size_t)(q0 + row) * DD + col];
            float4v v0 = src[0], v1 = src[1];
            hv[0]=(_Float16)v0[0]; hv[1]=(_Float16)v0[1]; hv[2]=(_Float16)v0[2]; hv[3]=(_Float16)v0[3];
            hv[4]=(_Float16)v1[0]; hv[5]=(_Float16)v1[1]; hv[6]=(_Float16)v1[2]; hv[7]=(_Float16)v1[3];
        } else {
            #pragma unroll
            for (int j = 0; j < 8; ++j) hv[j] = (_Float16)0.f;
        }
        *(half8*)&Qf[(size_t)e * 8] = hv;
    }
    __syncthreads();

    float4v o[4][8];
    #pragma unroll
    for (int qf = 0; qf < 4; ++qf)
        #pragma unroll
        for (int dt = 0; dt < 8; ++dt)
            o[qf][dt] = (float4v){0.f, 0.f, 0.f, 0.f};

    float m_run[16], l_run[16];
    #pragma unroll
    for (int i = 0; i < 16; ++i) { m_run[i] = -INFINITY; l_run[i] = 0.f; }

    const int pbase = w * 512 + q4 * 32 + ((ln >> 3) << 7) + (ln & 7);
    half8 pa[4];

    for (int it = 0; it < ITERS; ++it) {
        // ---- phase 1: S[64 q][wave's 32 keys], full-D (VGPR path) ----
        const _Float16* kp0 = Kf + (size_t)(ks * 256 + it * 16 + w * 2) * 16384 + (size_t)l * 8;
        float4v sa[4][2];
        #pragma unroll
        for (int qf = 0; qf < 4; ++qf) {
            sa[qf][0] = (float4v){0.f, 0.f, 0.f, 0.f};
            sa[qf][1] = (float4v){0.f, 0.f, 0.f, 0.f};
        }
        #pragma unroll 4
        for (int kk = 0; kk < QKK; ++kk) {
            half8 k0 = *(const half8*)(kp0 + kk * 512);
            half8 k1 = *(const half8*)(kp0 + 16384 + kk * 512);
            #pragma unroll
            for (int qf = 0; qf < 4; ++qf) {
                half8 qa = *(const half8*)&Qf[((qf * QKK + kk) * 64 + l) * 8];
                sa[qf][0] = __builtin_amdgcn_mfma_f32_16x16x32_f16(qa, k0, sa[qf][0], 0, 0, 0);
                sa[qf][1] = __builtin_amdgcn_mfma_f32_16x16x32_f16(qa, k1, sa[qf][1], 0, 0, 0);
            }
        }
        #pragma unroll 4
        for (int kk = QKK; kk < 32; ++kk) {
            half8 k0 = *(const half8*)(kp0 + kk * 512);
            half8 k1 = *(const half8*)(kp0 + 16384 + kk * 512);
            #pragma unroll
            for (int qf = 0; qf < 4; ++qf) {
                half8 qa = *(const half8*)(Qg + (((size_t)(qt * 4 + qf) * 32 + kk) << 9) + (l << 3));
                sa[qf][0] = __builtin_amdgcn_mfma_f32_16x16x32_f16(qa, k0, sa[qf][0], 0, 0, 0);
                sa[qf][1] = __builtin_amdgcn_mfma_f32_16x16x32_f16(qa, k1, sa[qf][1], 0, 0, 0);
            }
        }

        const int kbase = ks * KHALF + it * BK + w * 32;
        const bool bad0 = (kbase + ln) >= NK;
        const bool bad1 = (kbase + 16 + ln) >= NK;

        // ---- wave-local row max ----
        float pm[16];
        #pragma unroll
        for (int qf = 0; qf < 4; ++qf)
            #pragma unroll
            for (int r = 0; r < 4; ++r) {
                float v0 = bad0 ? -INFINITY : sa[qf][0][r];
                float v1 = bad1 ? -INFINITY : sa[qf][1][r];
                pm[qf * 4 + r] = fmaxf(v0, v1);
            }
        #pragma unroll
        for (int i = 0; i < 16; ++i) {
            float v = pm[i];
            v = fmaxf(v, __shfl_xor(v, 1, 64));
            v = fmaxf(v, __shfl_xor(v, 2, 64));
            v = fmaxf(v, __shfl_xor(v, 4, 64));
            v = fmaxf(v, __shfl_xor(v, 8, 64));
            pm[i] = v;
        }
        if (ln == 0) {
            #pragma unroll
            for (int qf = 0; qf < 4; ++qf)
                #pragma unroll
                for (int r = 0; r < 4; ++r)
                    Rm[w * BQ + qf * 16 + q4 * 4 + r] = pm[qf * 4 + r];
        }
        __syncthreads();   // B: Rm visible (drains all phase-1 VMEM -> vmcnt 0)

        // ---- global row max, alpha ----
        const _Float16* vbase = Vf + (((size_t)(ks * 128 + it * 8)) << 9) + (l << 3);
        float al[16];
        #pragma unroll
        for (int qf = 0; qf < 4; ++qf)
            #pragma unroll
            for (int r = 0; r < 4; ++r) {
                int row = qf * 16 + q4 * 4 + r;
                int i = qf * 4 + r;
                float v = m_run[i];
                #pragma unroll
                for (int wv = 0; wv < NW; ++wv) v = fmaxf(v, Rm[wv * BQ + row]);
                al[i] = __expf(m_run[i] - v);
                m_run[i] = v;
            }

        // ---- V-ring prologue: slots for sub-steps 0,1,2 (kk2=0, dt 0..5) ----
        IVF(VSA, 0, 0);
        IVF(VSB, 2, 0);
        IVF(VSC, 4, 0);

        // ---- exp, P write, l update, O rescale ----
        #pragma unroll
        for (int i = 0; i < 16; ++i) l_run[i] *= al[i];
        #pragma unroll
        for (int qf = 0; qf < 4; ++qf)
            #pragma unroll
            for (int r = 0; r < 4; ++r) {
                int i = qf * 4 + r;
                float p0 = bad0 ? 0.f : __expf(sa[qf][0][r] - m_run[i]);
                float p1 = bad1 ? 0.f : __expf(sa[qf][1][r] - m_run[i]);
                l_run[i] += p0 + p1;
                Pf[pbase + qf * 4096 + r * 8]       = (_Float16)p0;
                Pf[pbase + qf * 4096 + r * 8 + 256] = (_Float16)p1;
            }
        #pragma unroll
        for (int qf = 0; qf < 4; ++qf)
            #pragma unroll
            for (int dt = 0; dt < 8; ++dt)
                #pragma unroll
                for (int r = 0; r < 4; ++r)
                    o[qf][dt][r] *= al[qf * 4 + r];
        __syncthreads();   // D: Pf ready (also drains prologue -> slots 0-2 ready)

        // ---- phase 3: O += P.V via DMA ring, 32 static sub-steps ----
        PV3(0,  VSA, NOWAIT, IVF(VSA, 6, 0));
        PV3(1,  VSB, NOWAIT, IVF(VSB, 0, 1));
        PV3(2,  VSC, NOWAIT, IVF(VSC, 2, 1));
        PV3(3,  VSA, W4,     IVF(VSA, 4, 1));
        PV3(4,  VSB, W4,     IVF(VSB, 6, 1));
        PV3(5,  VSC, W4,     IVF(VSC, 0, 2));
        PV3(6,  VSA, W4,     IVF(VSA, 2, 2));
        PV3(7,  VSB, W4,     IVF(VSB, 4, 2));
        PV3(8,  VSC, W4,     IVF(VSC, 6, 2));
        PV3(9,  VSA, W4,     IVF(VSA, 0, 3));
        PV3(10, VSB, W4,     IVF(VSB, 2, 3));
        PV3(11, VSC, W4,     IVF(VSC, 4, 3));
        PV3(12, VSA, W4,     IVF(VSA, 6, 3));
        PV3(13, VSB, W4,     IVF(VSB, 0, 4));
        PV3(14, VSC, W4,     IVF(VSC, 2, 4));
        PV3(15, VSA, W4,     IVF(VSA, 4, 4));
        PV3(16, VSB, W4,     IVF(VSB, 6, 4));
        PV3(17, VSC, W4,     IVF(VSC, 0, 5));
        PV3(18, VSA, W4,     IVF(VSA, 2, 5));
        PV3(19, VSB, W4,     IVF(VSB, 4, 5));
        PV3(20, VSC, W4,     IVF(VSC, 6, 5));
        PV3(21, VSA, W4,     IVF(VSA, 0, 6));
        PV3(22, VSB, W4,     IVF(VSB, 2, 6));
        PV3(23, VSC, W4,     IVF(VSC, 4, 6));
        PV3(24, VSA, W4,     IVF(VSA, 6, 6));
        PV3(25, VSB, W4,     IVF(VSB, 0, 7));
        PV3(26, VSC, W4,     IVF(VSC, 2, 7));
        PV3(27, VSA, W4,     IVF(VSA, 4, 7));
        PV3(28, VSB, W4,     IVF(VSB, 6, 7));
        PV3(29, VSC, W4,     NOFILL);
        PV3(30, VSA, W2,     NOFILL);
        PV3(31, VSB, W0,     NOFILL);
        __syncthreads();   // A: Pf/Rm free for next iter
    }

    // ---- epilogue: reduce l across lanes and waves, store partials ----
    float lt[16];
    #pragma unroll
    for (int i = 0; i < 16; ++i) {
        float v = l_run[i];
        v += __shfl_xor(v, 1, 64);
        v += __shfl_xor(v, 2, 64);
        v += __shfl_xor(v, 4, 64);
        v += __shfl_xor(v, 8, 64);
        lt[i] = v;
    }
    if (ln == 0) {
        #pragma unroll
        for (int qf = 0; qf < 4; ++qf)
            #pragma unroll
            for (int r = 0; r < 4; ++r)
                Rm[w * BQ + qf * 16 + q4 * 4 + r] = lt[qf * 4 + r];
    }
    __syncthreads();

    float lsum[16], inv[16];
    #pragma unroll
    for (int qf = 0; qf < 4; ++qf)
        #pragma unroll
        for (int r = 0; r < 4; ++r) {
            int row = qf * 16 + q4 * 4 + r;
            float sum = 0.f;
            #pragma unroll
            for (int wv = 0; wv < NW; ++wv) sum += Rm[wv * BQ + row];
            lsum[qf * 4 + r] = sum;
            inv[qf * 4 + r] = 1.f / sum;
        }

    if (w == 0 && ln == 0) {
        #pragma unroll
        for (int qf = 0; qf < 4; ++qf)
            #pragma unroll
            for (int r = 0; r < 4; ++r) {
                int row = q0 + qf * 16 + q4 * 4 + r;
                int i = qf * 4 + r;
                if (row < NQ)
                    ml[ks * 8192 + row] = make_float2(m_run[i], lsum[i]);
            }
    }

    #pragma unroll
    for (int qf = 0; qf < 4; ++qf)
        #pragma unroll
        for (int dt = 0; dt < 8; ++dt)
            #pragma unroll
            for (int r = 0; r < 4; ++r) {
                int row = q0 + qf * 16 + q4 * 4 + r;
                int col = w * 128 + dt * 16 + ln;
                if (row < NQ)
                    Op[((size_t)ks * NQ + row) * DD + col] =
                        (_Float16)(o[qf][dt][r] * inv[qf * 4 + r]);
            }
}

// out = w0 * Op[0] + w1 * Op[1], weights from (m,l) pairs
__global__ void combine(const _Float16* __restrict__ Op,
                        const float2* __restrict__ ml,
                        float* __restrict__ out) {
    size_t idx = ((size_t)blockIdx.x * 256 + threadIdx.x) * 8;
    if (idx >= (size_t)NQ * DD) return;
    int row = (int)(idx >> 10);
    float2 a = ml[row];
    float2 b = ml[8192 + row];
    float m  = fmaxf(a.x, b.x);
    float w0 = a.y * __expf(a.x - m);
    float w1 = b.y * __expf(b.x - m);
    float inv = 1.f / (w0 + w1);
    w0 *= inv; w1 *= inv;
    half8 h0 = *(const half8*)&Op[idx];
    half8 h1 = *(const half8*)&Op[(size_t)NQ * DD + idx];
    float4v o0, o1;
    #pragma unroll
    for (int e = 0; e < 4; ++e) o0[e] = w0 * (float)h0[e] + w1 * (float)h1[e];
    #pragma unroll
    for (int e = 0; e < 4; ++e) o1[e] = w0 * (float)h0[e + 4] + w1 * (float)h1[e + 4];
    *(float4v*)&out[idx]     = o0;
    *(float4v*)&out[idx + 4] = o1;
}

extern "C" void kernel_launch(void* const* d_in, const int* in_sizes, int n_in,
                              void* d_out, int out_size, void* d_ws, size_t ws_size,
                              hipStream_t stream) {
    const float* X = (const float*)d_in[0];
    const float* s = (const float*)d_in[1];
    float* out = (float*)d_out;

    _Float16* Kf = (_Float16*)d_ws;                  // 16 MiB
    _Float16* Vf = Kf + (size_t)8192 * 1024;         // 16 MiB
    _Float16* Qg = Vf + (size_t)8192 * 1024;         // 16 MiB
    _Float16* Op = Qg + (size_t)8192 * 1024;         // 32 MiB
    float2*   ml = (float2*)(Op + (size_t)2 * NQ * DD);  // 128 KiB

    prep_kf<<<4096, 256, 0, stream>>>(X, Kf);
    prep_vf<<<4096, 256, 0, stream>>>(X, Vf);
    prep_qf<<<4096, 256, 0, stream>>>(s, Qg);
    flash<<<KSPLIT * ((NQ + BQ - 1) / BQ), NT, 0, stream>>>(s, Qg, Kf, Vf, Op, ml);
    combine<<<4096, 256, 0, stream>>>(Op, ml, out);
}